// Round 10
// baseline (13124.205 us; speedup 1.0000x reference)
//
#include <hip/hip_runtime.h>
#include <hip/hip_cooperative_groups.h>

namespace cg = cooperative_groups;

#define NN 2048
#define NB 32
#define NT 500
#define WGS 512
#define NWG 256

// Persistent cooperative kernel. R10 == R9 design (compile fix only):
// per-step readiness via 8 padded global counters (2 parity x 4 waves; one
// atomicAdd per producer wave per step, 4 polling threads per consumer WG),
// payload via coherent VECTOR loads/stores (sc0 sc1 = bypass L1/L2, straight
// to coherence point; they coalesce, unlike atomics). Atomic-op volume drops
// ~100x vs R7/R8. No cache-invalidating fences anywhere (R4's 105 GB lesson).
//
// Safety: WG reaches step s's poll only after publishing step s (cnt[p] is
// cumulative; target grows 256/round). cnt[p]==256k implies every WG finished
// reading buf[p^1] for step s-1 before publishing s -> overwriting buf[p^1]
// with step s+1 data is safe (2-step skew impossible). Replay-safe: counters
// re-zeroed in init before the single cg grid.sync; step 0 skips the exchange
// entirely (known all-zero spikes).
//
// Compute body == R3 (validated 3x): WG owns 8 rows; thread (rh4,jh,b) does
// 4 rows x 256-consecutive-j sequential chunk (x,y,z,w bit order); chunks
// combined 0..7 in order by the (row,b) owner thread. Bit-exact order kept.
//
// ws: buf u64[2][1024] @0 (16 KB) | cnt u32[2*4*32] @16384 (1 KB, counters
//     at stride 32 u32 = 128 B) | xT f32[500][32] @17408 | wgpart @81408

__device__ __forceinline__ uint4 load_coh16(const void* p) {
    uint4 v;
    asm volatile("global_load_dwordx4 %0, %1, off sc0 sc1\n\t"
                 "s_waitcnt vmcnt(0)"
                 : "=&v"(v) : "v"(p) : "memory");
    return v;
}

__device__ __forceinline__ void store_coh8(void* p, unsigned long long v) {
    asm volatile("global_store_dwordx2 %0, %1, off sc0 sc1"
                 :: "v"(p), "v"(v) : "memory");
}

__launch_bounds__(WGS)
__global__ void reservoir_kernel(const float* __restrict__ x,
                                 const float* __restrict__ W,
                                 const float* __restrict__ bias,
                                 float* __restrict__ out,
                                 void* __restrict__ wsv)
{
    cg::grid_group grid = cg::this_grid();

    __shared__ unsigned int lbits[NN];      // 8 KB spike bits
    __shared__ float lpart[8][8][32];       // 8 KB [jh][row][b]
    __shared__ int   lcnt[4];

    unsigned long long* buf = (unsigned long long*)wsv;              // [2][1024]
    unsigned int* cnt       = (unsigned int*)((char*)wsv + 16384);   // [2*4*32]
    float* xT               = (float*)((char*)wsv + 17408);          // [500][32]
    int*   wgpart           = (int*)((char*)wsv + 81408);            // [256]

    const int wg = blockIdx.x;
    const int t  = threadIdx.x;
    const int i0 = wg * 8;

    // init: counters zeroed (replay safety), x transposed to xT[step][b]
    if (wg == 0 && t < 8)
        __hip_atomic_store(&cnt[t * 32], 0u,
                           __ATOMIC_RELAXED, __HIP_MEMORY_SCOPE_AGENT);
    for (int g = wg * WGS + t; g < NT * NB; g += NWG * WGS)
        xT[g] = x[(size_t)(g & 31) * NT + (g >> 5)];

    // compute identity (== R3): 4 rows per thread
    const int rh4 = (t >> 8) * 4;      // 0 or 4
    const int jh  = (t >> 5) & 7;      // chunk 0..7
    const int b   = t & 31;            // batch

    const float4* __restrict__ wr0 = (const float4*)(W + (size_t)(i0 + rh4 + 0) * NN) + jh * 64;
    const float4* __restrict__ wr1 = (const float4*)(W + (size_t)(i0 + rh4 + 1) * NN) + jh * 64;
    const float4* __restrict__ wr2 = (const float4*)(W + (size_t)(i0 + rh4 + 2) * NN) + jh * 64;
    const float4* __restrict__ wr3 = (const float4*)(W + (size_t)(i0 + rh4 + 3) * NN) + jh * 64;

    // combine identity (t < 256): (row cil, batch cb), state in registers
    const int cil = t >> 5;
    const int cb  = t & 31;
    const float biasv = (t < 256) ? bias[i0 + cil] : 0.0f;
    float mem = 0.0f;
    int   scount = 0;

    float* spk_rec = out + 1;
    float* mem_rec = out + 1 + (size_t)NT * NB * NN;

    grid.sync();   // init visibility (once)

    unsigned int tgt0 = 0, tgt1 = 0;

    for (int step = 0; step < NT; ++step) {
        const int pcur = step & 1;

        if (step == 0) {
            // spikes known all-zero: no exchange
            ((uint4*)lbits)[t] = make_uint4(0u, 0u, 0u, 0u);
        } else {
            if (pcur) tgt1 += 256; else tgt0 += 256;
            const unsigned int tg = pcur ? tgt1 : tgt0;
            if (t < 4) {
                while (__hip_atomic_load(&cnt[(pcur * 4 + t) * 32], __ATOMIC_RELAXED,
                                         __HIP_MEMORY_SCOPE_AGENT) < tg)
                    __builtin_amdgcn_s_sleep(1);
            }
            __syncthreads();   // (B0) data ready grid-wide

            uint4 v = load_coh16((const char*)(buf + (size_t)pcur * 1024) + 16 * t);
            *(uint4*)&lbits[4 * t] = v;
        }
        const float xv = (t < 256) ? xT[step * NB + cb] : 0.0f;
        __syncthreads();   // (B) lbits staged

        // chunk partial: 4 rows x 1 batch over 256 consecutive j (bit-exact order)
        float c0 = 0.0f, c1 = 0.0f, c2 = 0.0f, c3 = 0.0f;
        const uint4* bp = ((const uint4*)lbits) + jh * 64;
        #pragma unroll 2
        for (int jj = 0; jj < 64; ++jj) {
            const float4 w0 = wr0[jj];
            const float4 w1 = wr1[jj];
            const float4 w2 = wr2[jj];
            const float4 w3 = wr3[jj];
            const uint4  bu = bp[jj];
            float s;
            s = (float)((bu.x >> b) & 1u);
            c0 = fmaf(w0.x, s, c0); c1 = fmaf(w1.x, s, c1);
            c2 = fmaf(w2.x, s, c2); c3 = fmaf(w3.x, s, c3);
            s = (float)((bu.y >> b) & 1u);
            c0 = fmaf(w0.y, s, c0); c1 = fmaf(w1.y, s, c1);
            c2 = fmaf(w2.y, s, c2); c3 = fmaf(w3.y, s, c3);
            s = (float)((bu.z >> b) & 1u);
            c0 = fmaf(w0.z, s, c0); c1 = fmaf(w1.z, s, c1);
            c2 = fmaf(w2.z, s, c2); c3 = fmaf(w3.z, s, c3);
            s = (float)((bu.w >> b) & 1u);
            c0 = fmaf(w0.w, s, c0); c1 = fmaf(w1.w, s, c1);
            c2 = fmaf(w2.w, s, c2); c3 = fmaf(w3.w, s, c3);
        }
        lpart[jh][rh4 + 0][b] = c0;
        lpart[jh][rh4 + 1][b] = c1;
        lpart[jh][rh4 + 2][b] = c2;
        lpart[jh][rh4 + 3][b] = c3;
        __syncthreads();   // (C) lpart ready

        if (t < 256) {
            // sequential combine over chunks (bit-exact validated order)
            float d = lpart[0][cil][cb];
            #pragma unroll
            for (int k = 1; k < 8; ++k) d += lpart[k][cil][cb];

            const float sp = (float)((lbits[i0 + cil] >> cb) & 1u);

            float base = 0.95f * mem + xv + d + biasv;
            float nm   = base * (1.0f - sp);
            float ns   = (nm > 1.0f) ? 1.0f : 0.0f;
            mem = nm;
            scount += (int)ns;

            // publish: one coherent 8B store per wave -> vmcnt -> one atomicAdd
            unsigned long long bal = __ballot(ns > 0.5f);  // lo32=row 2w2, hi32=row 2w2+1
            const int l  = t & 63;
            const int w2 = t >> 6;
            const int pnxt = pcur ^ 1;
            if (l == 0)
                store_coh8((char*)(buf + (size_t)pnxt * 1024) + 8 * (4 * wg + w2), bal);
            asm volatile("s_waitcnt vmcnt(0)" ::: "memory");
            if (l == 0)
                __hip_atomic_fetch_add(&cnt[(pnxt * 4 + w2) * 32], 1u,
                                       __ATOMIC_RELAXED, __HIP_MEMORY_SCOPE_AGENT);

            // record stores (plain, L2-merged; off critical path)
            size_t o = ((size_t)step * NB + cb) * (size_t)NN + i0 + cil;
            spk_rec[o] = ns;
            mem_rec[o] = nm;
        }
        // no trailing barrier needed: step s+1's lbits write happens after
        // its (B0)+(B) barriers, which order it after this step's combine
        // reads of lbits within the WG.
    }

    // average firing rate (scount==0 for t>=256)
    #pragma unroll
    for (int d2 = 1; d2 < 64; d2 <<= 1) scount += __shfl_xor(scount, d2, 64);
    if ((t & 63) == 0 && t < 256) lcnt[t >> 6] = scount;
    __syncthreads();
    if (t == 0) wgpart[wg] = lcnt[0] + lcnt[1] + lcnt[2] + lcnt[3];
    grid.sync();
    if (wg == 0) {
        int ps = (t < NWG) ? wgpart[t] : 0;
        #pragma unroll
        for (int d2 = 1; d2 < 64; d2 <<= 1) ps += __shfl_xor(ps, d2, 64);
        if ((t & 63) == 0 && t < 256) lcnt[t >> 6] = ps;
        __syncthreads();
        if (t == 0) {
            long long s2 = (long long)lcnt[0] + lcnt[1] + lcnt[2] + lcnt[3];
            out[0] = (float)((double)s2 / (double)((long long)NT * NB * NN));
        }
    }
}

extern "C" void kernel_launch(void* const* d_in, const int* in_sizes, int n_in,
                              void* d_out, int out_size, void* d_ws, size_t ws_size,
                              hipStream_t stream) {
    const float* x    = (const float*)d_in[0];  // (32, 500, 1)
    const float* W    = (const float*)d_in[1];  // (2048, 2048)
    const float* bias = (const float*)d_in[2];  // (2048,)
    float* out = (float*)d_out;
    void*  ws  = d_ws;

    void* args[] = { (void*)&x, (void*)&W, (void*)&bias, (void*)&out, (void*)&ws };
    hipLaunchCooperativeKernel((const void*)reservoir_kernel,
                               dim3(NWG), dim3(WGS), args, 0, stream);
}